// Round 11
// baseline (330.979 us; speedup 1.0000x reference)
//
#include <hip/hip_runtime.h>
#include <cmath>

// ---------------------------------------------------------------------------
// SpectralGAT: 2-layer GAT (H1=4,C1=128 concat -> 512; H=1,C2=64) + MLP.
// bf16 MFMA GEMMs (global_load_lds staging, both-sides swizzle); scores fused
// into GEMM epilogues; SINGLE-PASS flash-style conv1 aggregation; conv2
// aggregation fused with the MLP head; rank-based CSR fill from edge_index.
// ---------------------------------------------------------------------------

#define F_IN 128
#define H1   4
#define C1   128
#define D1   512   // H1*C1
#define C2   64
#define DM1  32
#define DM2  16

#define LRELU(x) ((x) > 0.f ? (x) : 0.2f * (x))

typedef float f32x4 __attribute__((ext_vector_type(4)));
typedef short short8 __attribute__((ext_vector_type(8)));

static __device__ __forceinline__ float bf2f(unsigned short u) {
    return __builtin_bit_cast(float, (unsigned)u << 16);
}
static __device__ __forceinline__ unsigned short f2bf(float f) {
    unsigned u = __builtin_bit_cast(unsigned, f);
    u = (u + 0x7fffu + ((u >> 16) & 1u)) >> 16;
    return (unsigned short)u;
}
static __device__ __forceinline__ float bflo(unsigned d) {
    return __builtin_bit_cast(float, d << 16);
}
static __device__ __forceinline__ float bfhi(unsigned d) {
    return __builtin_bit_cast(float, d & 0xffff0000u);
}

// --------------------------- edge dtype detect ------------------------------
__global__ void k_detect(const void* ei, int E, int* flag) {
    __shared__ int any;
    if (threadIdx.x == 0) any = 0;
    __syncthreads();
    const int* p = (const int*)ei;
    int cnt = E < 4096 ? E : 4096;
    int stride = E / cnt;
    int local = 0;
    for (int i = threadIdx.x; i < cnt; i += blockDim.x) {
        long long idx = (long long)i * stride;
        local |= p[2 * idx + 1];
    }
    if (local) atomicOr(&any, 1);
    __syncthreads();
    if (threadIdx.x == 0) *flag = (any == 0) ? 1 : 0;
}

// fused: degree count + per-edge rank AND x/W1/W2 bf16 prep
__global__ void k_convert_prep(const void* ei, const int* flag, int E, int N,
                               int* deg, int* rank32,
                               const float* __restrict__ x,
                               const float* __restrict__ W1,
                               const float* __restrict__ W2,
                               unsigned short* __restrict__ xb,
                               unsigned short* __restrict__ W1t,
                               unsigned short* __restrict__ W2t, int n8) {
    int i = blockIdx.x * blockDim.x + threadIdx.x;
    int Etot = E + N;
    if (i < Etot) {
        int d;
        if (i < E) {
            if (*flag) {
                const long long* q = (const long long*)ei;
                d = (int)q[(size_t)E + i];
            } else {
                const int* q = (const int*)ei;
                d = q[(size_t)E + i];
            }
        } else {
            d = i - E;
        }
        rank32[i] = atomicAdd(&deg[d], 1);
        return;
    }
    int i1 = i - Etot;
    if (i1 < n8) {
        const float4* p = (const float4*)(x + (size_t)i1 * 8);
        float4 a = p[0], b = p[1];
        unsigned short r[8] = {f2bf(a.x), f2bf(a.y), f2bf(a.z), f2bf(a.w),
                               f2bf(b.x), f2bf(b.y), f2bf(b.z), f2bf(b.w)};
        *(short8*)(xb + (size_t)i1 * 8) = *(const short8*)r;
        return;
    }
    int i2 = i1 - n8;
    if (i2 < F_IN * D1) {  // W1t[n*F_IN+k] = W1[k*D1+n]
        int nn = i2 / F_IN, kk = i2 - nn * F_IN;
        W1t[i2] = f2bf(W1[(size_t)kk * D1 + nn]);
        return;
    }
    int i3 = i2 - F_IN * D1;
    if (i3 < D1 * C2) {  // W2t[n*D1+k] = W2[k*C2+n]
        int nn = i3 / D1, kk = i3 - nn * D1;
        W2t[i3] = f2bf(W2[(size_t)kk * C2 + nn]);
    }
}

// --------------------------- parallel scan (3 phases) -----------------------
__global__ __launch_bounds__(256) void k_scan1(const int* __restrict__ deg,
                                               int* __restrict__ bsum, int N) {
    int t = threadIdx.x;
    int base = blockIdx.x * 1024 + t * 4;
    int s = 0;
    if (base + 3 < N) {
        int4 v = *(const int4*)&deg[base];
        s = v.x + v.y + v.z + v.w;
    } else {
        for (int k = 0; k < 4; k++)
            if (base + k < N) s += deg[base + k];
    }
#pragma unroll
    for (int o = 1; o < 64; o <<= 1) s += __shfl_xor(s, o, 64);
    __shared__ int ws[4];
    if ((t & 63) == 0) ws[t >> 6] = s;
    __syncthreads();
    if (t == 0) bsum[blockIdx.x] = ws[0] + ws[1] + ws[2] + ws[3];
}

__global__ __launch_bounds__(1024) void k_scan2(const int* __restrict__ bsum,
                                                int* __restrict__ boff, int nb) {
    __shared__ int wsum[16];
    __shared__ int woff[16];
    int t = threadIdx.x, lane = t & 63, wid = t >> 6;
    int v = (t < nb) ? bsum[t] : 0;
    int x = v;
#pragma unroll
    for (int o = 1; o < 64; o <<= 1) {
        int tv = __shfl_up(x, o, 64);
        if (lane >= o) x += tv;
    }
    if (lane == 63) wsum[wid] = x;
    __syncthreads();
    if (wid == 0) {
        int y = (lane < 16) ? wsum[lane] : 0;
        int z = y;
#pragma unroll
        for (int o = 1; o < 16; o <<= 1) {
            int tv = __shfl_up(z, o, 64);
            if (lane >= o) z += tv;
        }
        if (lane < 16) woff[lane] = z - y;
    }
    __syncthreads();
    if (t < nb) boff[t] = woff[wid] + x - v;
}

__global__ __launch_bounds__(256) void k_scan3(const int* __restrict__ deg,
                                               const int* __restrict__ boff,
                                               int* __restrict__ rowstart, int N,
                                               int Etot) {
    int t = threadIdx.x, lane = t & 63, wid = t >> 6;
    int base = blockIdx.x * 1024 + t * 4;
    int v0 = 0, v1 = 0, v2 = 0, v3 = 0;
    if (base + 3 < N) {
        int4 v = *(const int4*)&deg[base];
        v0 = v.x; v1 = v.y; v2 = v.z; v3 = v.w;
    } else {
        if (base + 0 < N) v0 = deg[base + 0];
        if (base + 1 < N) v1 = deg[base + 1];
        if (base + 2 < N) v2 = deg[base + 2];
        if (base + 3 < N) v3 = deg[base + 3];
    }
    int s4 = v0 + v1 + v2 + v3;
    int x = s4;
#pragma unroll
    for (int o = 1; o < 64; o <<= 1) {
        int tv = __shfl_up(x, o, 64);
        if (lane >= o) x += tv;
    }
    __shared__ int ws[4];
    if (lane == 63) ws[wid] = x;
    __syncthreads();
    int woff = 0;
#pragma unroll
    for (int w = 0; w < 4; w++)
        if (w < wid) woff += ws[w];
    int ex = boff[blockIdx.x] + woff + (x - s4);
    int e0 = ex, e1 = ex + v0, e2 = e1 + v1, e3 = e2 + v2;
    if (base + 0 < N) rowstart[base + 0] = e0;
    if (base + 1 < N) rowstart[base + 1] = e1;
    if (base + 2 < N) rowstart[base + 2] = e2;
    if (base + 3 < N) rowstart[base + 3] = e3;
    if (blockIdx.x == 0 && t == 0) rowstart[N] = Etot;
}

// rank-based fill straight from edge_index: no atomics, no src32/dst32
__global__ void k_fill(const void* ei, const int* flag, int E, int N,
                       const int* __restrict__ rank32,
                       const int* __restrict__ rowstart, int* __restrict__ adj,
                       int Etot) {
    int i = blockIdx.x * blockDim.x + threadIdx.x;
    if (i >= Etot) return;
    int s, d;
    if (i < E) {
        if (*flag) {
            const long long* q = (const long long*)ei;
            s = (int)q[i];
            d = (int)q[(size_t)E + i];
        } else {
            const int* q = (const int*)ei;
            s = q[i];
            d = q[(size_t)E + i];
        }
    } else {
        s = i - E;
        d = i - E;
    }
    adj[rowstart[d] + rank32[i]] = s;
}

// --------------------------- bf16 MFMA GEMM (+fused scores) -----------------
// C[M,NC] = A[M,K] @ Bt[NC,K]^T.  K % 64 == 0.  256 threads = 4 waves.
// Staging: global_load_lds width=16, linear LDS dest, source pre-swizzled so
// ds_read applies unit ^= (row&7)  (rule-21 both-sides swizzle).
// SC_MODE: 0=none, 1=per-head scores (s[gr*H1+blockIdx.y], a-vec flat[gc]),
//          2=full-row scores (s[gr]).
template <int WM, int WN, int MF, int NF, bool OUT_BF16, int SC_MODE>
__global__ __launch_bounds__(256) void k_gemm_bf16(
    const unsigned short* __restrict__ A, const unsigned short* __restrict__ Bt,
    void* __restrict__ C, int M, int K, int NC,
    const float* __restrict__ avs, const float* __restrict__ avd,
    float* __restrict__ s_src, float* __restrict__ s_dst) {
    constexpr int BM = WM * MF * 16;
    constexpr int BN = WN * NF * 16;
    constexpr int BK = 64;  // 8 units of 16B per row
    __shared__ unsigned short As[BM * BK];
    __shared__ unsigned short Bs[BN * BK];
    __shared__ float ps_lds[WN][BM], pd_lds[WN][BM];
    const int tid = threadIdx.x;
    const int row0 = blockIdx.x * BM, col0 = blockIdx.y * BN;
    const int wave = tid >> 6, lane = tid & 63;
    const int wr = wave / WN, wc = wave % WN;
    const int lrow = lane & 15, lkg = lane >> 4;
    f32x4 acc[MF][NF] = {};
    for (int k0 = 0; k0 < K; k0 += BK) {
#pragma unroll
        for (int inst = 0; inst < (BM * 8) / 256; ++inst) {
            int ibase = inst * 256 + wave * 64;
            int i = ibase + lane;
            int r = i >> 3, u = i & 7, su = u ^ (r & 7);
            const unsigned short* gp = A + (size_t)(row0 + r) * K + k0 + su * 8;
            __builtin_amdgcn_global_load_lds(
                (const __attribute__((address_space(1))) void*)gp,
                (__attribute__((address_space(3))) void*)&As[ibase * 8], 16, 0, 0);
        }
#pragma unroll
        for (int inst = 0; inst < (BN * 8) / 256; ++inst) {
            int ibase = inst * 256 + wave * 64;
            int i = ibase + lane;
            int r = i >> 3, u = i & 7, su = u ^ (r & 7);
            const unsigned short* gp = Bt + (size_t)(col0 + r) * K + k0 + su * 8;
            __builtin_amdgcn_global_load_lds(
                (const __attribute__((address_space(1))) void*)gp,
                (__attribute__((address_space(3))) void*)&Bs[ibase * 8], 16, 0, 0);
        }
        __syncthreads();
#pragma unroll
        for (int kk = 0; kk < BK; kk += 32) {
            short8 af[MF], bfr[NF];
#pragma unroll
            for (int m = 0; m < MF; m++) {
                int ar = wr * MF * 16 + m * 16 + lrow;
                int au = kk / 8 + lkg;
                af[m] = *(const short8*)&As[(ar * 8 + (au ^ (lrow & 7))) * 8];
            }
#pragma unroll
            for (int n = 0; n < NF; n++) {
                int br = wc * NF * 16 + n * 16 + lrow;
                int au = kk / 8 + lkg;
                bfr[n] = *(const short8*)&Bs[(br * 8 + (au ^ (lrow & 7))) * 8];
            }
#pragma unroll
            for (int m = 0; m < MF; m++)
#pragma unroll
                for (int n = 0; n < NF; n++)
                    acc[m][n] = __builtin_amdgcn_mfma_f32_16x16x32_bf16(
                        af[m], bfr[n], acc[m][n], 0, 0, 0);
        }
        __syncthreads();
    }
    // C store
#pragma unroll
    for (int m = 0; m < MF; m++)
#pragma unroll
        for (int n = 0; n < NF; n++)
#pragma unroll
            for (int r = 0; r < 4; r++) {
                int gr = row0 + wr * MF * 16 + m * 16 + lkg * 4 + r;
                int gc = col0 + wc * NF * 16 + n * 16 + lrow;
                if (gr < M) {
                    if (OUT_BF16)
                        ((unsigned short*)C)[(size_t)gr * NC + gc] = f2bf(acc[m][n][r]);
                    else
                        ((float*)C)[(size_t)gr * NC + gc] = acc[m][n][r];
                }
            }
    // fused attention scores from f32 accumulators
    if (SC_MODE) {
        float asv[NF], adv[NF];
#pragma unroll
        for (int n = 0; n < NF; n++) {
            int gc = col0 + wc * NF * 16 + n * 16 + lrow;
            asv[n] = avs[gc];
            adv[n] = avd[gc];
        }
#pragma unroll
        for (int m = 0; m < MF; m++)
#pragma unroll
            for (int r = 0; r < 4; r++) {
                float ps = 0.f, pd = 0.f;
#pragma unroll
                for (int n = 0; n < NF; n++) {
                    ps += acc[m][n][r] * asv[n];
                    pd += acc[m][n][r] * adv[n];
                }
#pragma unroll
                for (int o = 1; o < 16; o <<= 1) {
                    ps += __shfl_xor(ps, o, 64);
                    pd += __shfl_xor(pd, o, 64);
                }
                if (lrow == 0) {
                    int lr = wr * MF * 16 + m * 16 + lkg * 4 + r;
                    ps_lds[wc][lr] = ps;
                    pd_lds[wc][lr] = pd;
                }
            }
        __syncthreads();
        for (int rr = tid; rr < BM; rr += 256) {
            int gr = row0 + rr;
            if (gr < M) {
                float s = 0.f, d = 0.f;
#pragma unroll
                for (int w = 0; w < WN; w++) {
                    s += ps_lds[w][rr];
                    d += pd_lds[w][rr];
                }
                if (SC_MODE == 1) {
                    s_src[(size_t)gr * H1 + blockIdx.y] = s;
                    s_dst[(size_t)gr * H1 + blockIdx.y] = d;
                } else {
                    s_src[gr] = s;
                    s_dst[gr] = d;
                }
            }
        }
    }
}

// --------------------------- conv1 aggregate: single-pass flash -------------
// One edge pass: per chunk of 16 edges, (edge,head) lanes compute e, 4-level
// shfl chunk-max per head, rescale acc by exp(m_old-m_new), stash (src,av) in
// LDS (wave-synchronous lgkmcnt(0)), gather bf16 rows. Final 1/dn normalize.
__global__ __launch_bounds__(256) void k_agg1(
    const unsigned short* __restrict__ h1b, const float* __restrict__ s_src,
    const float* __restrict__ s_dst, const int* __restrict__ rowstart,
    const int* __restrict__ adj, const float* __restrict__ b1,
    unsigned short* __restrict__ out1, int N) {
    __shared__ uint2 ex_lds[4][64];
    int wv = (blockIdx.x * blockDim.x + threadIdx.x) >> 6;
    if (wv >= N) return;
    int wv4 = (threadIdx.x >> 6) & 3;
    int lane = threadIdx.x & 63;
    int beg = rowstart[wv], end = rowstart[wv + 1];
    int h4 = lane & 3, jj = lane >> 2, hg = lane >> 4;
    float sdh = s_dst[(size_t)wv * 4 + h4];
    int nch = (end - beg + 15) >> 4;
    float m = -1e30f, dn = 0.f;
    float aL[4] = {}, aH[4] = {};
#define ACC1(vv, aa)                                        \
    do {                                                    \
        aL[0] += (aa)*bflo(vv.x); aH[0] += (aa)*bfhi(vv.x); \
        aL[1] += (aa)*bflo(vv.y); aH[1] += (aa)*bfhi(vv.y); \
        aL[2] += (aa)*bflo(vv.z); aH[2] += (aa)*bfhi(vv.z); \
        aL[3] += (aa)*bflo(vv.w); aH[3] += (aa)*bfhi(vv.w); \
    } while (0)
    for (int c = 0; c < nch; ++c) {
        int j = beg + c * 16 + jj;
        float e = -1e30f;
        int sj = 0;
        if (j < end) {
            sj = adj[j];
            e = LRELU(s_src[(size_t)sj * 4 + h4] + sdh);
        }
        // chunk max per head (16 lanes at stride 4 share h4)
        float mc = e;
#pragma unroll
        for (int o = 4; o < 64; o <<= 1) mc = fmaxf(mc, __shfl_xor(mc, o, 64));
        float mn = fmaxf(m, mc);
        float scale = __expf(m - mn);  // first chunk: exp(-huge)=0
        float av = (j < end) ? __expf(e - mn) : 0.f;
        dn = dn * scale + av;
        m = mn;
        ex_lds[wv4][lane] = make_uint2((unsigned)sj, __builtin_bit_cast(unsigned, av));
        asm volatile("s_waitcnt lgkmcnt(0)" ::: "memory");
        float sg = __shfl(scale, hg, 64);
#pragma unroll
        for (int i = 0; i < 4; i++) { aL[i] *= sg; aH[i] *= sg; }
        int cnt = min(16, end - beg - c * 16);
        int j2 = 0;
        for (; j2 + 4 <= cnt; j2 += 4) {
            uint2 e0 = ex_lds[wv4][(j2 + 0) * 4 + hg];
            uint2 e1 = ex_lds[wv4][(j2 + 1) * 4 + hg];
            uint2 e2 = ex_lds[wv4][(j2 + 2) * 4 + hg];
            uint2 e3 = ex_lds[wv4][(j2 + 3) * 4 + hg];
            uint4 v0 = *(const uint4*)&h1b[(size_t)e0.x * D1 + lane * 8];
            uint4 v1 = *(const uint4*)&h1b[(size_t)e1.x * D1 + lane * 8];
            uint4 v2 = *(const uint4*)&h1b[(size_t)e2.x * D1 + lane * 8];
            uint4 v3 = *(const uint4*)&h1b[(size_t)e3.x * D1 + lane * 8];
            float a0 = __builtin_bit_cast(float, e0.y);
            float a1 = __builtin_bit_cast(float, e1.y);
            float a2 = __builtin_bit_cast(float, e2.y);
            float a3 = __builtin_bit_cast(float, e3.y);
            ACC1(v0, a0); ACC1(v1, a1); ACC1(v2, a2); ACC1(v3, a3);
        }
        for (; j2 < cnt; ++j2) {
            uint2 e0 = ex_lds[wv4][j2 * 4 + hg];
            uint4 v0 = *(const uint4*)&h1b[(size_t)e0.x * D1 + lane * 8];
            float a0 = __builtin_bit_cast(float, e0.y);
            ACC1(v0, a0);
        }
    }
#undef ACC1
    // total denom per head, then broadcast to gather lanes
#pragma unroll
    for (int o = 4; o < 64; o <<= 1) dn += __shfl_xor(dn, o, 64);
    float inv = 1.f / (dn + 1e-16f);
    float ig = __shfl(inv, hg, 64);
    const float4* bp = (const float4*)&b1[lane * 8];
    float4 bb0 = bp[0], bb1 = bp[1];
    float r[8];
    r[0] = aL[0] * ig + bb0.x; r[1] = aH[0] * ig + bb0.y;
    r[2] = aL[1] * ig + bb0.z; r[3] = aH[1] * ig + bb0.w;
    r[4] = aL[2] * ig + bb1.x; r[5] = aH[2] * ig + bb1.y;
    r[6] = aL[3] * ig + bb1.z; r[7] = aH[3] * ig + bb1.w;
    unsigned short o16[8];
#pragma unroll
    for (int i = 0; i < 8; i++) {
        float z = r[i] > 0.f ? r[i] : expm1f(r[i]);
        o16[i] = f2bf(z);
    }
    *(short8*)&out1[(size_t)wv * D1 + lane * 8] = *(const short8*)o16;
}

// --------------------------- conv2 aggregate + MLP head ---------------------
// Wave per node: softmax+gather (h2 row in regs, lanes<16 x 4ch), then the
// full MLP (64->32->LN->ReLU->16) in-wave via per-wave LDS redistribution.
__global__ __launch_bounds__(256) void k_agg2mlp(
    const unsigned short* __restrict__ h2lin, const float* __restrict__ s_src,
    const float* __restrict__ s_dst, const int* __restrict__ rowstart,
    const int* __restrict__ adj, const float* __restrict__ b2,
    const float* __restrict__ Wm1, const float* __restrict__ bm1,
    const float* __restrict__ g_ln, const float* __restrict__ b_ln,
    const float* __restrict__ Wm2, const float* __restrict__ bm2,
    float* __restrict__ out, int N) {
    __shared__ float w1[C2 * DM1];
    __shared__ float w2[DM1 * DM2];
    __shared__ float cb2[C2], cb1m[DM1], cg[DM1], cbl[DM1], cb2m[DM2];
    __shared__ float h_lds[4][C2];
    __shared__ float t_lds[4][DM1];
    int tid = threadIdx.x;
    for (int i = tid; i < C2 * DM1; i += 256) w1[i] = Wm1[i];
    for (int i = tid; i < DM1 * DM2; i += 256) w2[i] = Wm2[i];
    if (tid < C2) cb2[tid] = b2[tid];
    else if (tid < C2 + DM1) cb1m[tid - C2] = bm1[tid - C2];
    else if (tid < C2 + 2 * DM1) cg[tid - C2 - DM1] = g_ln[tid - C2 - DM1];
    else if (tid < C2 + 3 * DM1) cbl[tid - C2 - 2 * DM1] = b_ln[tid - C2 - 2 * DM1];
    else if (tid < C2 + 3 * DM1 + DM2) cb2m[tid - C2 - 3 * DM1] = bm2[tid - C2 - 3 * DM1];
    __syncthreads();
    int wv = (blockIdx.x * blockDim.x + tid) >> 6;
    if (wv >= N) return;
    int wv4 = (tid >> 6) & 3;
    int lane = tid & 63;
    int beg = rowstart[wv], end = rowstart[wv + 1];
    float sd = s_dst[wv];
    float m = -1e30f, dn = 0.f;
    for (int c0 = beg; c0 < end; c0 += 64) {
        int j = c0 + lane;
        float e = -1e30f;
        if (j < end) e = LRELU(s_src[adj[j]] + sd);
        float nm = fmaxf(m, e);
        dn = dn * __expf(m - nm) + ((j < end) ? __expf(e - nm) : 0.f);
        m = nm;
    }
#pragma unroll
    for (int o = 1; o < 64; o <<= 1) {
        float om = __shfl_xor(m, o, 64);
        float od = __shfl_xor(dn, o, 64);
        float nm = fmaxf(m, om);
        dn = dn * __expf(m - nm) + od * __expf(om - nm);
        m = nm;
    }
    float inv = 1.f / (dn + 1e-16f);
    int eg = lane >> 4, ch = (lane & 15) * 4;
    float a0 = 0.f, a1 = 0.f, a2 = 0.f, a3 = 0.f;
    for (int j0 = beg; j0 < end; j0 += 4) {
        int j = j0 + eg;
        if (j < end) {
            int sj = adj[j];
            float a = __expf(LRELU(s_src[sj] + sd) - m) * inv;
            uint2 rv = *(const uint2*)&h2lin[(size_t)sj * C2 + ch];
            a0 += a * bflo(rv.x); a1 += a * bfhi(rv.x);
            a2 += a * bflo(rv.y); a3 += a * bfhi(rv.y);
        }
    }
#pragma unroll
    for (int o = 16; o < 64; o <<= 1) {
        a0 += __shfl_xor(a0, o, 64);
        a1 += __shfl_xor(a1, o, 64);
        a2 += __shfl_xor(a2, o, 64);
        a3 += __shfl_xor(a3, o, 64);
    }
    if (lane < 16) {
        float r0 = a0 + cb2[ch], r1 = a1 + cb2[ch + 1];
        float r2 = a2 + cb2[ch + 2], r3 = a3 + cb2[ch + 3];
        r0 = r0 > 0.f ? r0 : expm1f(r0);
        r1 = r1 > 0.f ? r1 : expm1f(r1);
        r2 = r2 > 0.f ? r2 : expm1f(r2);
        r3 = r3 > 0.f ? r3 : expm1f(r3);
        *(float4*)&h_lds[wv4][ch] = make_float4(r0, r1, r2, r3);
    }
    asm volatile("s_waitcnt lgkmcnt(0)" ::: "memory");
    // MLP layer 1: lanes j and j+32 both compute t[j] (identical, all valid)
    int j = lane & 31;
    float t = cb1m[j];
#pragma unroll
    for (int c = 0; c < C2; c++) t += h_lds[wv4][c] * w1[c * DM1 + j];
    // LayerNorm over the 32 values (xor offsets < 32 stay within each half)
    float mu = t;
#pragma unroll
    for (int o = 1; o < 32; o <<= 1) mu += __shfl_xor(mu, o, 64);
    mu *= (1.f / DM1);
    float dv = t - mu, var = dv * dv;
#pragma unroll
    for (int o = 1; o < 32; o <<= 1) var += __shfl_xor(var, o, 64);
    var *= (1.f / DM1);
    float rs = rsqrtf(var + 1e-5f);
    float z = (t - mu) * rs * cg[j] + cbl[j];
    z = fmaxf(z, 0.f);
    if (lane < 32) t_lds[wv4][lane] = z;
    asm volatile("s_waitcnt lgkmcnt(0)" ::: "memory");
    if (lane < 16) {
        float a = cb2m[lane];
#pragma unroll
        for (int j2 = 0; j2 < DM1; j2++) a += t_lds[wv4][j2] * w2[j2 * DM2 + lane];
        out[(size_t)wv * DM2 + lane] = a;
    }
}

// ---------------------------------------------------------------------------
extern "C" void kernel_launch(void* const* d_in, const int* in_sizes, int n_in,
                              void* d_out, int out_size, void* d_ws,
                              size_t ws_size, hipStream_t stream) {
    const float* x      = (const float*)d_in[0];
    const void*  ei     = d_in[1];
    const float* W1     = (const float*)d_in[3];
    const float* a_src1 = (const float*)d_in[4];
    const float* a_dst1 = (const float*)d_in[5];
    const float* b1     = (const float*)d_in[6];
    const float* W2     = (const float*)d_in[7];
    const float* a_src2 = (const float*)d_in[8];
    const float* a_dst2 = (const float*)d_in[9];
    const float* b2     = (const float*)d_in[10];
    const float* Wm1    = (const float*)d_in[11];
    const float* bm1    = (const float*)d_in[12];
    const float* g_ln   = (const float*)d_in[13];
    const float* b_ln   = (const float*)d_in[14];
    const float* Wm2    = (const float*)d_in[15];
    const float* bm2    = (const float*)d_in[16];

    const int N    = in_sizes[0] / F_IN;
    const int E    = in_sizes[1] / 2;
    const int Etot = E + N;
    const int nb   = (N + 1023) / 1024;

    char* ws = (char*)d_ws;
    size_t off = 0;
    auto alloc = [&](size_t bytes) {
        size_t o = off;
        off += (bytes + 255) & ~(size_t)255;
        return o;
    };
    int*   flag     = (int*)(ws + alloc(4));
    int*   rank32   = (int*)(ws + alloc((size_t)Etot * 4));
    int*   deg      = (int*)(ws + alloc((size_t)N * 4));
    int*   bsum     = (int*)(ws + alloc(4096 * 4));
    int*   boff     = (int*)(ws + alloc(4096 * 4));
    int*   rowstart = (int*)(ws + alloc((size_t)(N + 1) * 4));
    int*   adj      = (int*)(ws + alloc((size_t)Etot * 4));
    float* s_src1   = (float*)(ws + alloc((size_t)N * H1 * 4));
    float* s_dst1   = (float*)(ws + alloc((size_t)N * H1 * 4));
    unsigned short* xb    = (unsigned short*)(ws + alloc((size_t)N * F_IN * 2));
    unsigned short* W1t   = (unsigned short*)(ws + alloc((size_t)F_IN * D1 * 2));
    unsigned short* W2t   = (unsigned short*)(ws + alloc((size_t)D1 * C2 * 2));
    unsigned short* h1b   = (unsigned short*)(ws + alloc((size_t)N * D1 * 2));
    unsigned short* out1  = (unsigned short*)(ws + alloc((size_t)N * D1 * 2));
    unsigned short* h2lin = (unsigned short*)(ws + alloc((size_t)N * C2 * 2));
    float* s_src2 = s_src1;
    float* s_dst2 = s_dst1;

    hipMemsetAsync(deg, 0, (size_t)N * 4, stream);
    k_detect<<<1, 256, 0, stream>>>(ei, E, flag);
    int n8 = N * F_IN / 8;
    int total_cp = Etot + n8 + F_IN * D1 + D1 * C2;
    k_convert_prep<<<(total_cp + 255) / 256, 256, 0, stream>>>(
        ei, flag, E, N, deg, rank32, x, W1, W2, xb, W1t, W2t, n8);
    k_scan1<<<nb, 256, 0, stream>>>(deg, bsum, N);
    k_scan2<<<1, 1024, 0, stream>>>(bsum, boff, nb);
    k_scan3<<<nb, 256, 0, stream>>>(deg, boff, rowstart, N, Etot);
    k_fill<<<(Etot + 255) / 256, 256, 0, stream>>>(ei, flag, E, N, rank32,
                                                   rowstart, adj, Etot);

    // conv1: h1 = x@W1 (scores fused: block col-range == one head)
    k_gemm_bf16<2, 2, 4, 4, true, 1>
        <<<dim3((N + 127) / 128, D1 / 128), 256, 0, stream>>>(
            xb, W1t, h1b, N, F_IN, D1, a_src1, a_dst1, s_src1, s_dst1);
    k_agg1<<<(N * 64 + 255) / 256, 256, 0, stream>>>(h1b, s_src1, s_dst1, rowstart,
                                                     adj, b1, out1, N);

    // conv2: h2lin = out1@W2 (bf16 out; 64x64 tile; scores fused over full C2)
    k_gemm_bf16<2, 2, 2, 2, true, 2>
        <<<dim3((N + 63) / 64, 1), 256, 0, stream>>>(
            out1, W2t, h2lin, N, D1, C2, a_src2, a_dst2, s_src2, s_dst2);

    // conv2 aggregate + fused MLP head
    k_agg2mlp<<<(N * 64 + 255) / 256, 256, 0, stream>>>(
        h2lin, s_src2, s_dst2, rowstart, adj, b2, Wm1, bm1, g_ln, b_ln, Wm2, bm2,
        (float*)d_out, N);
}